// Round 2
// baseline (553.742 us; speedup 1.0000x reference)
//
#include <hip/hip_runtime.h>

typedef __attribute__((ext_vector_type(8))) short bf16x8;
typedef __attribute__((ext_vector_type(4))) float f32x4;
typedef __attribute__((ext_vector_type(4))) unsigned short u16x4;

#define MFMA16(a, b, c) __builtin_amdgcn_mfma_f32_16x16x32_bf16((a), (b), (c), 0, 0, 0)

__device__ __forceinline__ unsigned short f2bf(float f) {
    union { float f; unsigned int u; } x; x.f = f;
    unsigned int r = x.u + 0x7FFFu + ((x.u >> 16) & 1u);
    return (unsigned short)(r >> 16);
}
__device__ __forceinline__ float bf2f(unsigned short h) {
    union { unsigned int u; float f; } x; x.u = ((unsigned int)h) << 16;
    return x.f;
}
__device__ __forceinline__ void gload_lds16(const void* g, void* l) {
    __builtin_amdgcn_global_load_lds(
        (const __attribute__((address_space(1))) unsigned int*)g,
        (__attribute__((address_space(3))) unsigned int*)l,
        16, 0, 0);
}

// ---- x (fp32) -> hi/lo bf16 split, same layout ----
__global__ void split_x(const float* __restrict__ in, unsigned short* __restrict__ hi,
                        unsigned short* __restrict__ lo, int n) {
    int i = (blockIdx.x * blockDim.x + threadIdx.x) * 4;
    if (i >= n) return;
    float4 v = *(const float4*)(in + i);
    float vv[4] = {v.x, v.y, v.z, v.w};
    u16x4 h, l;
#pragma unroll
    for (int j = 0; j < 4; ++j) {
        unsigned short hh = f2bf(vv[j]);
        h[j] = hh;
        l[j] = f2bf(vv[j] - bf2f(hh));
    }
    *(u16x4*)(hi + i) = h;
    *(u16x4*)(lo + i) = l;
}

// ---- transpose fp32 [K][N] -> bf16 hi(/lo) [N][K] ----
__global__ void tsplit_k(const float* __restrict__ in, unsigned short* __restrict__ hi,
                         unsigned short* __restrict__ lo, int K, int N) {
    __shared__ float tile[64][65];
    int n0 = blockIdx.x * 64, k0 = blockIdx.y * 64;
    for (int i = threadIdx.x; i < 4096; i += 256) {
        int r = i >> 6, c = i & 63;
        tile[r][c] = in[(size_t)(k0 + r) * N + n0 + c];
    }
    __syncthreads();
    for (int i = threadIdx.x; i < 4096; i += 256) {
        int r = i >> 6, c = i & 63;
        float v = tile[c][r];
        unsigned short h = f2bf(v);
        hi[(size_t)(n0 + r) * K + k0 + c] = h;
        if (lo) lo[(size_t)(n0 + r) * K + k0 + c] = f2bf(v - bf2f(h));
    }
}

// ---- QKV GEMM, split-bf16 precision (hi*hi + hi*lo + lo*hi), scatter epilogue ----
__global__ __launch_bounds__(256, 2) void gemm1_split(
    const unsigned short* __restrict__ Ah, const unsigned short* __restrict__ Al,
    const unsigned short* __restrict__ Bh, const unsigned short* __restrict__ Bl,
    unsigned short* __restrict__ qout, unsigned short* __restrict__ kout,
    unsigned short* __restrict__ vtout) {
    const int K = 1024;
    __shared__ __align__(16) unsigned short sAh[4096], sAl[4096], sBh[4096], sBl[4096];
    int tid = threadIdx.x, lane = tid & 63, w = tid >> 6;
    int c = lane & 15, quad = lane >> 4;
    int wm = (w >> 1) * 64, wn = (w & 1) * 64;
    int m0 = blockIdx.y * 128, n0 = blockIdx.x * 128;

    f32x4 acc[4][4];
#pragma unroll
    for (int i = 0; i < 4; i++)
#pragma unroll
        for (int j = 0; j < 4; j++) acc[i][j] = (f32x4){0.f, 0.f, 0.f, 0.f};

    int c0 = tid, c1 = 256 + tid;
    int r0 = c0 >> 2, kc0 = (c0 & 3) * 8;
    int r1 = c1 >> 2, kc1 = (c1 & 3) * 8;

    for (int kk = 0; kk < K; kk += 32) {
        gload_lds16(Ah + (size_t)(m0 + r0) * K + kk + kc0, &sAh[c0 * 8]);
        gload_lds16(Ah + (size_t)(m0 + r1) * K + kk + kc1, &sAh[c1 * 8]);
        gload_lds16(Al + (size_t)(m0 + r0) * K + kk + kc0, &sAl[c0 * 8]);
        gload_lds16(Al + (size_t)(m0 + r1) * K + kk + kc1, &sAl[c1 * 8]);
        gload_lds16(Bh + (size_t)(n0 + r0) * K + kk + kc0, &sBh[c0 * 8]);
        gload_lds16(Bh + (size_t)(n0 + r1) * K + kk + kc1, &sBh[c1 * 8]);
        gload_lds16(Bl + (size_t)(n0 + r0) * K + kk + kc0, &sBl[c0 * 8]);
        gload_lds16(Bl + (size_t)(n0 + r1) * K + kk + kc1, &sBl[c1 * 8]);
        __syncthreads();
        bf16x8 ah[4], al[4], bh[4], bl[4];
#pragma unroll
        for (int mt = 0; mt < 4; ++mt) {
            ah[mt] = *(const bf16x8*)&sAh[(wm + mt * 16 + c) * 32 + quad * 8];
            al[mt] = *(const bf16x8*)&sAl[(wm + mt * 16 + c) * 32 + quad * 8];
        }
#pragma unroll
        for (int nt = 0; nt < 4; ++nt) {
            bh[nt] = *(const bf16x8*)&sBh[(wn + nt * 16 + c) * 32 + quad * 8];
            bl[nt] = *(const bf16x8*)&sBl[(wn + nt * 16 + c) * 32 + quad * 8];
        }
#pragma unroll
        for (int mt = 0; mt < 4; ++mt)
#pragma unroll
            for (int nt = 0; nt < 4; ++nt) {
                acc[mt][nt] = MFMA16(ah[mt], bh[nt], acc[mt][nt]);
                acc[mt][nt] = MFMA16(ah[mt], bl[nt], acc[mt][nt]);
                acc[mt][nt] = MFMA16(al[mt], bh[nt], acc[mt][nt]);
            }
        __syncthreads();
    }

    const float QSCALE = 0.1803368801111601f;  // log2(e) / sqrt(64)
#pragma unroll
    for (int mt = 0; mt < 4; ++mt) {
#pragma unroll
        for (int nt = 0; nt < 4; ++nt) {
#pragma unroll
            for (int r = 0; r < 4; ++r) {
                int row = m0 + wm + mt * 16 + quad * 4 + r;
                int col = n0 + wn + nt * 16 + c;
                float v = acc[mt][nt][r];
                int which = col >> 10;
                int h = (col >> 6) & 15;
                int d = col & 63;
                int b = row >> 11;
                int t = row & 2047;
                size_t bh_ = (size_t)(b * 16 + h);
                if (which == 0)
                    qout[(bh_ * 2048 + t) * 64 + d] = f2bf(v * QSCALE);
                else if (which == 1)
                    kout[(bh_ * 2048 + t) * 64 + d] = f2bf(v);
                else
                    vtout[(bh_ * 64 + d) * 2048 + t] = f2bf(v);
            }
        }
    }
}

// ---- output GEMM, plain bf16, fp32 store ----
__global__ __launch_bounds__(256, 2) void gemm2_bt(
    const unsigned short* __restrict__ A,    // 8192 x 1024 bf16
    const unsigned short* __restrict__ Bt,   // 1024 x 1024 bf16
    float* __restrict__ out) {
    const int K = 1024, N = 1024;
    __shared__ __align__(16) unsigned short sA[4096], sB[4096];
    int tid = threadIdx.x, lane = tid & 63, w = tid >> 6;
    int c = lane & 15, quad = lane >> 4;
    int wm = (w >> 1) * 64, wn = (w & 1) * 64;
    int m0 = blockIdx.y * 128, n0 = blockIdx.x * 128;

    f32x4 acc[4][4];
#pragma unroll
    for (int i = 0; i < 4; i++)
#pragma unroll
        for (int j = 0; j < 4; j++) acc[i][j] = (f32x4){0.f, 0.f, 0.f, 0.f};

    int c0 = tid, c1 = 256 + tid;
    int r0 = c0 >> 2, kc0 = (c0 & 3) * 8;
    int r1 = c1 >> 2, kc1 = (c1 & 3) * 8;

    for (int kk = 0; kk < K; kk += 32) {
        gload_lds16(A + (size_t)(m0 + r0) * K + kk + kc0, &sA[c0 * 8]);
        gload_lds16(A + (size_t)(m0 + r1) * K + kk + kc1, &sA[c1 * 8]);
        gload_lds16(Bt + (size_t)(n0 + r0) * K + kk + kc0, &sB[c0 * 8]);
        gload_lds16(Bt + (size_t)(n0 + r1) * K + kk + kc1, &sB[c1 * 8]);
        __syncthreads();
        bf16x8 af[4], bfr[4];
#pragma unroll
        for (int mt = 0; mt < 4; ++mt)
            af[mt] = *(const bf16x8*)&sA[(wm + mt * 16 + c) * 32 + quad * 8];
#pragma unroll
        for (int nt = 0; nt < 4; ++nt)
            bfr[nt] = *(const bf16x8*)&sB[(wn + nt * 16 + c) * 32 + quad * 8];
#pragma unroll
        for (int mt = 0; mt < 4; ++mt)
#pragma unroll
            for (int nt = 0; nt < 4; ++nt)
                acc[mt][nt] = MFMA16(af[mt], bfr[nt], acc[mt][nt]);
        __syncthreads();
    }

#pragma unroll
    for (int mt = 0; mt < 4; ++mt)
#pragma unroll
        for (int nt = 0; nt < 4; ++nt)
#pragma unroll
            for (int r = 0; r < 4; ++r) {
                int row = m0 + wm + mt * 16 + quad * 4 + r;
                int col = n0 + wn + nt * 16 + c;
                out[(size_t)row * N + col] = acc[mt][nt][r];
            }
}

// ---- causal flash attention (bf16 q/k/vt, bf16 ctx out) ----
#define SSTR 72
__global__ __launch_bounds__(256, 2) void attn_k(
    const unsigned short* __restrict__ q,
    const unsigned short* __restrict__ k,
    const unsigned short* __restrict__ vt,
    unsigned short* __restrict__ ctx) {
    const int T = 2048, D = 64;
    __shared__ __align__(16) unsigned short sK[64 * SSTR];
    __shared__ __align__(16) unsigned short sV[64 * SSTR];
    __shared__ __align__(16) unsigned short sP[64 * SSTR];

    int tid = threadIdx.x, lane = tid & 63, w = tid >> 6;
    int c = lane & 15, quad = lane >> 4;
    int qt = blockIdx.x, bh = blockIdx.y;
    int q0 = qt * 64;

    const unsigned short* qh = q + (size_t)bh * T * D;
    const unsigned short* kh = k + (size_t)bh * T * D;
    const unsigned short* vh = vt + (size_t)bh * D * T;

    bf16x8 aq0 = *(const bf16x8*)&qh[(size_t)(q0 + w * 16 + c) * D + quad * 8];
    bf16x8 aq1 = *(const bf16x8*)&qh[(size_t)(q0 + w * 16 + c) * D + 32 + quad * 8];

    f32x4 o[4];
#pragma unroll
    for (int nt = 0; nt < 4; ++nt) o[nt] = (f32x4){0.f, 0.f, 0.f, 0.f};
    float m_i[4], l_i[4];
#pragma unroll
    for (int r = 0; r < 4; ++r) { m_i[r] = -1.0e30f; l_i[r] = 0.f; }

    for (int kt = 0; kt <= qt; ++kt) {
        int kb = kt * 64;
        __syncthreads();  // previous iteration's LDS reads done
        {   // stage K tile [key][d]
            int t = lane, d0 = w * 8;
            *(bf16x8*)&sK[t * SSTR + d0] = *(const bf16x8*)&kh[(size_t)(kb + t) * D + d0];
            *(bf16x8*)&sK[t * SSTR + d0 + 32] =
                *(const bf16x8*)&kh[(size_t)(kb + t) * D + d0 + 32];
        }
        {   // stage V^T tile [d][key]
#pragma unroll
            for (int p = 0; p < 2; ++p) {
                int id = p * 256 + tid;
                int d = id >> 3, tc = (id & 7) * 8;
                *(bf16x8*)&sV[d * SSTR + tc] = *(const bf16x8*)&vh[(size_t)d * T + kb + tc];
            }
        }
        __syncthreads();

        // S = Q K^T (log2 domain; Q pre-scaled)
        f32x4 s[4];
#pragma unroll
        for (int nt = 0; nt < 4; ++nt) s[nt] = (f32x4){0.f, 0.f, 0.f, 0.f};
#pragma unroll
        for (int nt = 0; nt < 4; ++nt) {
            bf16x8 b0 = *(const bf16x8*)&sK[(nt * 16 + c) * SSTR + quad * 8];
            bf16x8 b1 = *(const bf16x8*)&sK[(nt * 16 + c) * SSTR + 32 + quad * 8];
            s[nt] = MFMA16(aq0, b0, s[nt]);
            s[nt] = MFMA16(aq1, b1, s[nt]);
        }
        if (kt == qt) {
#pragma unroll
            for (int nt = 0; nt < 4; ++nt)
#pragma unroll
                for (int r = 0; r < 4; ++r)
                    if (nt * 16 + c > w * 16 + quad * 4 + r) s[nt][r] = -1.0e30f;
        }

        float mnew[4], alpha[4], rs[4];
#pragma unroll
        for (int r = 0; r < 4; ++r) {
            float v = fmaxf(fmaxf(s[0][r], s[1][r]), fmaxf(s[2][r], s[3][r]));
            v = fmaxf(v, __shfl_xor(v, 1));
            v = fmaxf(v, __shfl_xor(v, 2));
            v = fmaxf(v, __shfl_xor(v, 4));
            v = fmaxf(v, __shfl_xor(v, 8));
            mnew[r] = fmaxf(m_i[r], v);
            alpha[r] = __builtin_exp2f(m_i[r] - mnew[r]);
            rs[r] = 0.f;
        }
#pragma unroll
        for (int nt = 0; nt < 4; ++nt)
#pragma unroll
            for (int r = 0; r < 4; ++r) {
                float p = __builtin_exp2f(s[nt][r] - mnew[r]);
                unsigned short pb = f2bf(p);
                rs[r] += bf2f(pb);  // sum what PV will actually use
                sP[(w * 16 + quad * 4 + r) * SSTR + nt * 16 + c] = pb;
            }
#pragma unroll
        for (int r = 0; r < 4; ++r) {
            float v = rs[r];
            v += __shfl_xor(v, 1);
            v += __shfl_xor(v, 2);
            v += __shfl_xor(v, 4);
            v += __shfl_xor(v, 8);
            l_i[r] = l_i[r] * alpha[r] + v;
            m_i[r] = mnew[r];
        }
#pragma unroll
        for (int nt = 0; nt < 4; ++nt)
#pragma unroll
            for (int r = 0; r < 4; ++r) o[nt][r] *= alpha[r];

        __syncthreads();  // sP writes visible before PV fragment reads

#pragma unroll
        for (int kk2 = 0; kk2 < 64; kk2 += 32) {
            bf16x8 ap = *(const bf16x8*)&sP[(w * 16 + c) * SSTR + kk2 + quad * 8];
#pragma unroll
            for (int nt = 0; nt < 4; ++nt) {
                bf16x8 bv = *(const bf16x8*)&sV[(nt * 16 + c) * SSTR + kk2 + quad * 8];
                o[nt] = MFMA16(ap, bv, o[nt]);
            }
        }
    }

    int b = bh >> 4, h = bh & 15;
#pragma unroll
    for (int r = 0; r < 4; ++r) {
        float inv = 1.0f / l_i[r];
        int t = q0 + w * 16 + quad * 4 + r;
#pragma unroll
        for (int nt = 0; nt < 4; ++nt)
            ctx[(size_t)(b * T + t) * 1024 + h * 64 + nt * 16 + c] =
                f2bf(o[nt][r] * inv);
    }
}

extern "C" void kernel_launch(void* const* d_in, const int* in_sizes, int n_in,
                              void* d_out, int out_size, void* d_ws, size_t ws_size,
                              hipStream_t stream) {
    const float* x     = (const float*)d_in[0];  // (4,2048,1024) fp32
    const float* w_qkv = (const float*)d_in[1];  // (1024,3072) fp32
    const float* w_out = (const float*)d_in[2];  // (1024,1024) fp32
    float* out = (float*)d_out;                  // (4,2048,1024) fp32

    char* ws = (char*)d_ws;
    unsigned short* wqkvt_h = (unsigned short*)(ws + 0);          //  6.29 MB
    unsigned short* wqkvt_l = (unsigned short*)(ws + 6291456);    //  6.29 MB
    unsigned short* wout_t  = (unsigned short*)(ws + 12582912);   //  2.10 MB
    unsigned short* x_hi    = (unsigned short*)(ws + 14680064);   // 16.78 MB
    unsigned short* x_lo    = (unsigned short*)(ws + 31457280);   // 16.78 MB
    unsigned short* qb      = (unsigned short*)(ws + 48234496);   // 16.78 MB
    unsigned short* kb      = (unsigned short*)(ws + 65011712);   // 16.78 MB
    unsigned short* vtb     = (unsigned short*)(ws + 81788928);   // 16.78 MB
    unsigned short* ctx     = (unsigned short*)(ws + 14680064);   // reuse x_hi slot (x dead after gemm1)

    split_x<<<8192, 256, 0, stream>>>(x, x_hi, x_lo, 8388608);
    tsplit_k<<<dim3(48, 16), 256, 0, stream>>>(w_qkv, wqkvt_h, wqkvt_l, 1024, 3072);
    tsplit_k<<<dim3(16, 16), 256, 0, stream>>>(w_out, wout_t, nullptr, 1024, 1024);
    gemm1_split<<<dim3(24, 64), 256, 0, stream>>>(x_hi, x_lo, wqkvt_h, wqkvt_l,
                                                  qb, kb, vtb);
    attn_k<<<dim3(32, 64), 256, 0, stream>>>(qb, kb, vtb, ctx);
    gemm2_bt<<<dim3(8, 64), 256, 0, stream>>>(ctx, wout_t, out);
}

// Round 4
// 403.784 us; speedup vs baseline: 1.3714x; 1.3714x over previous
//
#include <hip/hip_runtime.h>

typedef __attribute__((ext_vector_type(8))) short bf16x8;
typedef __attribute__((ext_vector_type(4))) float f32x4;
typedef __attribute__((ext_vector_type(4))) unsigned short u16x4;

#define MFMA16(a, b, c) __builtin_amdgcn_mfma_f32_16x16x32_bf16((a), (b), (c), 0, 0, 0)

__device__ __forceinline__ unsigned short f2bf(float f) {
    union { float f; unsigned int u; } x; x.f = f;
    unsigned int r = x.u + 0x7FFFu + ((x.u >> 16) & 1u);
    return (unsigned short)(r >> 16);
}
__device__ __forceinline__ float bf2f(unsigned short h) {
    union { unsigned int u; float f; } x; x.u = ((unsigned int)h) << 16;
    return x.f;
}
__device__ __forceinline__ void gload_lds16(const void* g, void* l) {
    __builtin_amdgcn_global_load_lds(
        (const __attribute__((address_space(1))) unsigned int*)g,
        (__attribute__((address_space(3))) unsigned int*)l,
        16, 0, 0);
}

// ---- x (fp32) -> hi/lo bf16 split, same layout ----
__global__ void split_x(const float* __restrict__ in, unsigned short* __restrict__ hi,
                        unsigned short* __restrict__ lo, int n) {
    int i = (blockIdx.x * blockDim.x + threadIdx.x) * 4;
    if (i >= n) return;
    float4 v = *(const float4*)(in + i);
    float vv[4] = {v.x, v.y, v.z, v.w};
    u16x4 h, l;
#pragma unroll
    for (int j = 0; j < 4; ++j) {
        unsigned short hh = f2bf(vv[j]);
        h[j] = hh;
        l[j] = f2bf(vv[j] - bf2f(hh));
    }
    *(u16x4*)(hi + i) = h;
    *(u16x4*)(lo + i) = l;
}

// ---- transpose fp32 [K][N] -> bf16 hi(/lo) [N][K] ----
__global__ void tsplit_k(const float* __restrict__ in, unsigned short* __restrict__ hi,
                         unsigned short* __restrict__ lo, int K, int N) {
    __shared__ float tile[64][65];
    int n0 = blockIdx.x * 64, k0 = blockIdx.y * 64;
    for (int i = threadIdx.x; i < 4096; i += 256) {
        int r = i >> 6, c = i & 63;
        tile[r][c] = in[(size_t)(k0 + r) * N + n0 + c];
    }
    __syncthreads();
    for (int i = threadIdx.x; i < 4096; i += 256) {
        int r = i >> 6, c = i & 63;
        float v = tile[c][r];
        unsigned short h = f2bf(v);
        hi[(size_t)(n0 + r) * K + k0 + c] = h;
        if (lo) lo[(size_t)(n0 + r) * K + k0 + c] = f2bf(v - bf2f(h));
    }
}

// ---- QKV GEMM, split-bf16 precision (hi*hi + hi*lo + lo*hi), scatter epilogue ----
__global__ __launch_bounds__(256, 2) void gemm1_split(
    const unsigned short* __restrict__ Ah, const unsigned short* __restrict__ Al,
    const unsigned short* __restrict__ Bh, const unsigned short* __restrict__ Bl,
    unsigned short* __restrict__ qout, unsigned short* __restrict__ kout,
    unsigned short* __restrict__ vtout) {
    const int K = 1024;
    __shared__ __align__(16) unsigned short sAh[4096], sAl[4096], sBh[4096], sBl[4096];
    int tid = threadIdx.x, lane = tid & 63, w = tid >> 6;
    int c = lane & 15, quad = lane >> 4;
    int wm = (w >> 1) * 64, wn = (w & 1) * 64;
    int m0 = blockIdx.y * 128, n0 = blockIdx.x * 128;

    f32x4 acc[4][4];
#pragma unroll
    for (int i = 0; i < 4; i++)
#pragma unroll
        for (int j = 0; j < 4; j++) acc[i][j] = (f32x4){0.f, 0.f, 0.f, 0.f};

    int c0 = tid, c1 = 256 + tid;
    int r0 = c0 >> 2, kc0 = (c0 & 3) * 8;
    int r1 = c1 >> 2, kc1 = (c1 & 3) * 8;

    for (int kk = 0; kk < K; kk += 32) {
        gload_lds16(Ah + (size_t)(m0 + r0) * K + kk + kc0, &sAh[c0 * 8]);
        gload_lds16(Ah + (size_t)(m0 + r1) * K + kk + kc1, &sAh[c1 * 8]);
        gload_lds16(Al + (size_t)(m0 + r0) * K + kk + kc0, &sAl[c0 * 8]);
        gload_lds16(Al + (size_t)(m0 + r1) * K + kk + kc1, &sAl[c1 * 8]);
        gload_lds16(Bh + (size_t)(n0 + r0) * K + kk + kc0, &sBh[c0 * 8]);
        gload_lds16(Bh + (size_t)(n0 + r1) * K + kk + kc1, &sBh[c1 * 8]);
        gload_lds16(Bl + (size_t)(n0 + r0) * K + kk + kc0, &sBl[c0 * 8]);
        gload_lds16(Bl + (size_t)(n0 + r1) * K + kk + kc1, &sBl[c1 * 8]);
        __syncthreads();
        bf16x8 ah[4], al[4], bh[4], bl[4];
#pragma unroll
        for (int mt = 0; mt < 4; ++mt) {
            ah[mt] = *(const bf16x8*)&sAh[(wm + mt * 16 + c) * 32 + quad * 8];
            al[mt] = *(const bf16x8*)&sAl[(wm + mt * 16 + c) * 32 + quad * 8];
        }
#pragma unroll
        for (int nt = 0; nt < 4; ++nt) {
            bh[nt] = *(const bf16x8*)&sBh[(wn + nt * 16 + c) * 32 + quad * 8];
            bl[nt] = *(const bf16x8*)&sBl[(wn + nt * 16 + c) * 32 + quad * 8];
        }
#pragma unroll
        for (int mt = 0; mt < 4; ++mt)
#pragma unroll
            for (int nt = 0; nt < 4; ++nt) {
                acc[mt][nt] = MFMA16(ah[mt], bh[nt], acc[mt][nt]);
                acc[mt][nt] = MFMA16(ah[mt], bl[nt], acc[mt][nt]);
                acc[mt][nt] = MFMA16(al[mt], bh[nt], acc[mt][nt]);
            }
        __syncthreads();
    }

    const float QSCALE = 0.1803368801111601f;  // log2(e) / sqrt(64)
#pragma unroll
    for (int mt = 0; mt < 4; ++mt) {
#pragma unroll
        for (int nt = 0; nt < 4; ++nt) {
#pragma unroll
            for (int r = 0; r < 4; ++r) {
                int row = m0 + wm + mt * 16 + quad * 4 + r;
                int col = n0 + wn + nt * 16 + c;
                float v = acc[mt][nt][r];
                int which = col >> 10;
                int h = (col >> 6) & 15;
                int d = col & 63;
                int b = row >> 11;
                int t = row & 2047;
                size_t bh_ = (size_t)(b * 16 + h);
                if (which == 0)
                    qout[(bh_ * 2048 + t) * 64 + d] = f2bf(v * QSCALE);
                else if (which == 1)
                    kout[(bh_ * 2048 + t) * 64 + d] = f2bf(v);
                else
                    vtout[(bh_ * 64 + d) * 2048 + t] = f2bf(v);
            }
        }
    }
}

// ---- output GEMM, plain bf16, fp32 store ----
__global__ __launch_bounds__(256, 2) void gemm2_bt(
    const unsigned short* __restrict__ A,    // 8192 x 1024 bf16
    const unsigned short* __restrict__ Bt,   // 1024 x 1024 bf16
    float* __restrict__ out) {
    const int K = 1024, N = 1024;
    __shared__ __align__(16) unsigned short sA[4096], sB[4096];
    int tid = threadIdx.x, lane = tid & 63, w = tid >> 6;
    int c = lane & 15, quad = lane >> 4;
    int wm = (w >> 1) * 64, wn = (w & 1) * 64;
    int m0 = blockIdx.y * 128, n0 = blockIdx.x * 128;

    f32x4 acc[4][4];
#pragma unroll
    for (int i = 0; i < 4; i++)
#pragma unroll
        for (int j = 0; j < 4; j++) acc[i][j] = (f32x4){0.f, 0.f, 0.f, 0.f};

    int c0 = tid, c1 = 256 + tid;
    int r0 = c0 >> 2, kc0 = (c0 & 3) * 8;
    int r1 = c1 >> 2, kc1 = (c1 & 3) * 8;

    for (int kk = 0; kk < K; kk += 32) {
        gload_lds16(A + (size_t)(m0 + r0) * K + kk + kc0, &sA[c0 * 8]);
        gload_lds16(A + (size_t)(m0 + r1) * K + kk + kc1, &sA[c1 * 8]);
        gload_lds16(Bt + (size_t)(n0 + r0) * K + kk + kc0, &sB[c0 * 8]);
        gload_lds16(Bt + (size_t)(n0 + r1) * K + kk + kc1, &sB[c1 * 8]);
        __syncthreads();
        bf16x8 af[4], bfr[4];
#pragma unroll
        for (int mt = 0; mt < 4; ++mt)
            af[mt] = *(const bf16x8*)&sA[(wm + mt * 16 + c) * 32 + quad * 8];
#pragma unroll
        for (int nt = 0; nt < 4; ++nt)
            bfr[nt] = *(const bf16x8*)&sB[(wn + nt * 16 + c) * 32 + quad * 8];
#pragma unroll
        for (int mt = 0; mt < 4; ++mt)
#pragma unroll
            for (int nt = 0; nt < 4; ++nt)
                acc[mt][nt] = MFMA16(af[mt], bfr[nt], acc[mt][nt]);
        __syncthreads();
    }

#pragma unroll
    for (int mt = 0; mt < 4; ++mt)
#pragma unroll
        for (int nt = 0; nt < 4; ++nt)
#pragma unroll
            for (int r = 0; r < 4; ++r) {
                int row = m0 + wm + mt * 16 + quad * 4 + r;
                int col = n0 + wn + nt * 16 + c;
                out[(size_t)row * N + col] = acc[mt][nt][r];
            }
}

// ---- causal flash attention, S^T / O^T formulation ----
// Per wave: 16 q-rows (qrow = w*16 + c), K-tile = 64 keys.
// S^T = K·Q^T  (C-layout: col=lane&15=qrow, row=key)  -> softmax mostly per-lane
// O^T = V^T·P^T (col=qrow, row=d)
// Block pairs q-tiles (p, 31-p): every block runs exactly 33 K-tile iters.
#define SSTR 72
__global__ __launch_bounds__(256, 2) void attn_k(
    const unsigned short* __restrict__ q,
    const unsigned short* __restrict__ k,
    const unsigned short* __restrict__ vt,
    unsigned short* __restrict__ ctx) {
    const int T = 2048, D = 64;
    __shared__ __align__(16) unsigned short sK[64 * SSTR];    // [key][d]
    __shared__ __align__(16) unsigned short sV[64 * SSTR];    // [d][key]
    __shared__ __align__(16) unsigned short sP[4][16 * SSTR]; // per-wave [qrow][key]

    int tid = threadIdx.x, lane = tid & 63, w = tid >> 6;
    int c = lane & 15, quad = lane >> 4;
    int pair = blockIdx.x, bh = blockIdx.y;

    const unsigned short* qh = q + (size_t)bh * T * D;
    const unsigned short* kh = k + (size_t)bh * T * D;
    const unsigned short* vh = vt + (size_t)bh * D * T;
    unsigned short* sPw = sP[w];
    int b = bh >> 4, hh = bh & 15;

    for (int half = 0; half < 2; ++half) {
        int qt = half ? (31 - pair) : pair;
        int q0 = qt * 64;
        int qrow = q0 + w * 16 + c;

        // Q^T B-fragments: B^T[n=qrow][k=d] = q[qrow][d], 8 contiguous d
        bf16x8 bq0 = *(const bf16x8*)&qh[(size_t)qrow * D + quad * 8];
        bf16x8 bq1 = *(const bf16x8*)&qh[(size_t)qrow * D + 32 + quad * 8];

        f32x4 o[4];
#pragma unroll
        for (int mt = 0; mt < 4; ++mt) o[mt] = (f32x4){0.f, 0.f, 0.f, 0.f};
        float m_i = -1.0e30f, l_i = 0.f;

        for (int kt = 0; kt <= qt; ++kt) {
            int kb = kt * 64;
            __syncthreads();  // previous iteration's LDS reads complete
            {   // stage K tile [key][d]
                int t = lane, d0 = w * 8;
                *(bf16x8*)&sK[t * SSTR + d0] =
                    *(const bf16x8*)&kh[(size_t)(kb + t) * D + d0];
                *(bf16x8*)&sK[t * SSTR + d0 + 32] =
                    *(const bf16x8*)&kh[(size_t)(kb + t) * D + d0 + 32];
            }
            {   // stage V^T tile [d][key]
#pragma unroll
                for (int p = 0; p < 2; ++p) {
                    int id = p * 256 + tid;
                    int d = id >> 3, tc = (id & 7) * 8;
                    *(bf16x8*)&sV[d * SSTR + tc] =
                        *(const bf16x8*)&vh[(size_t)d * T + kb + tc];
                }
            }
            __syncthreads();

            // S^T = K · Q^T : lane holds 16 keys (mt*16+quad*4+r) for qrow c
            f32x4 st[4];
#pragma unroll
            for (int mt = 0; mt < 4; ++mt) {
                bf16x8 ak0 = *(const bf16x8*)&sK[(mt * 16 + c) * SSTR + quad * 8];
                bf16x8 ak1 = *(const bf16x8*)&sK[(mt * 16 + c) * SSTR + 32 + quad * 8];
                f32x4 z = (f32x4){0.f, 0.f, 0.f, 0.f};
                z = MFMA16(ak0, bq0, z);
                z = MFMA16(ak1, bq1, z);
                st[mt] = z;
            }
            if (kt == qt) {  // causal: key > qrow (tile-local indices)
                int qloc = w * 16 + c;
#pragma unroll
                for (int mt = 0; mt < 4; ++mt)
#pragma unroll
                    for (int r = 0; r < 4; ++r)
                        if (mt * 16 + quad * 4 + r > qloc) st[mt][r] = -1.0e30f;
            }

            // per-lane online softmax over this lane's 16 keys, then quad-combine
            float vmax = fmaxf(fmaxf(fmaxf(st[0][0], st[0][1]), fmaxf(st[0][2], st[0][3])),
                               fmaxf(fmaxf(st[1][0], st[1][1]), fmaxf(st[1][2], st[1][3])));
            float vmax2 = fmaxf(fmaxf(fmaxf(st[2][0], st[2][1]), fmaxf(st[2][2], st[2][3])),
                                fmaxf(fmaxf(st[3][0], st[3][1]), fmaxf(st[3][2], st[3][3])));
            vmax = fmaxf(vmax, vmax2);
            vmax = fmaxf(vmax, __shfl_xor(vmax, 16));
            vmax = fmaxf(vmax, __shfl_xor(vmax, 32));
            float mnew = fmaxf(m_i, vmax);
            float alpha = __builtin_exp2f(m_i - mnew);

            float rs = 0.f;
#pragma unroll
            for (int mt = 0; mt < 4; ++mt) {
                u16x4 pb;
#pragma unroll
                for (int r = 0; r < 4; ++r) {
                    float p = __builtin_exp2f(st[mt][r] - mnew);
                    unsigned short pw = f2bf(p);
                    rs += bf2f(pw);
                    pb[r] = pw;
                }
                // P^T handoff: P[qrow=c][keys mt*16+quad*4 .. +3] (wave-private rows)
                *(u16x4*)&sPw[c * SSTR + mt * 16 + quad * 4] = pb;
            }
            rs += __shfl_xor(rs, 16);
            rs += __shfl_xor(rs, 32);
            l_i = l_i * alpha + rs;
            m_i = mnew;
#pragma unroll
            for (int mt = 0; mt < 4; ++mt)
#pragma unroll
                for (int r = 0; r < 4; ++r) o[mt][r] *= alpha;

            // O^T += V^T · P^T  (A = sV[d][key], B = sPw[qrow][key])
#pragma unroll
            for (int ch = 0; ch < 2; ++ch) {
                bf16x8 bp = *(const bf16x8*)&sPw[c * SSTR + ch * 32 + quad * 8];
#pragma unroll
                for (int mt = 0; mt < 4; ++mt) {
                    bf16x8 av = *(const bf16x8*)&sV[(mt * 16 + c) * SSTR + ch * 32 + quad * 8];
                    o[mt] = MFMA16(av, bp, o[mt]);
                }
            }
        }

        // epilogue: lane owns qrow -> t = qrow ; d = mt*16 + quad*4 + r
        float inv = 1.0f / l_i;
#pragma unroll
        for (int mt = 0; mt < 4; ++mt) {
            u16x4 ob;
#pragma unroll
            for (int r = 0; r < 4; ++r) ob[r] = f2bf(o[mt][r] * inv);
            *(u16x4*)&ctx[(size_t)(b * T + qrow) * 1024 + hh * 64 + mt * 16 + quad * 4] = ob;
        }
    }
}

extern "C" void kernel_launch(void* const* d_in, const int* in_sizes, int n_in,
                              void* d_out, int out_size, void* d_ws, size_t ws_size,
                              hipStream_t stream) {
    const float* x     = (const float*)d_in[0];  // (4,2048,1024) fp32
    const float* w_qkv = (const float*)d_in[1];  // (1024,3072) fp32
    const float* w_out = (const float*)d_in[2];  // (1024,1024) fp32
    float* out = (float*)d_out;                  // (4,2048,1024) fp32

    char* ws = (char*)d_ws;
    unsigned short* wqkvt_h = (unsigned short*)(ws + 0);          //  6.29 MB
    unsigned short* wqkvt_l = (unsigned short*)(ws + 6291456);    //  6.29 MB
    unsigned short* wout_t  = (unsigned short*)(ws + 12582912);   //  2.10 MB
    unsigned short* x_hi    = (unsigned short*)(ws + 14680064);   // 16.78 MB
    unsigned short* x_lo    = (unsigned short*)(ws + 31457280);   // 16.78 MB
    unsigned short* qb      = (unsigned short*)(ws + 48234496);   // 16.78 MB
    unsigned short* kb      = (unsigned short*)(ws + 65011712);   // 16.78 MB
    unsigned short* vtb     = (unsigned short*)(ws + 81788928);   // 16.78 MB
    unsigned short* ctx     = (unsigned short*)(ws + 14680064);   // reuse x_hi slot

    split_x<<<8192, 256, 0, stream>>>(x, x_hi, x_lo, 8388608);
    tsplit_k<<<dim3(48, 16), 256, 0, stream>>>(w_qkv, wqkvt_h, wqkvt_l, 1024, 3072);
    tsplit_k<<<dim3(16, 16), 256, 0, stream>>>(w_out, wout_t, nullptr, 1024, 1024);
    gemm1_split<<<dim3(24, 64), 256, 0, stream>>>(x_hi, x_lo, wqkvt_h, wqkvt_l,
                                                  qb, kb, vtb);
    attn_k<<<dim3(16, 64), 256, 0, stream>>>(qb, kb, vtb, ctx);
    gemm2_bt<<<dim3(8, 64), 256, 0, stream>>>(ctx, wout_t, out);
}

// Round 5
// 314.004 us; speedup vs baseline: 1.7635x; 1.2859x over previous
//
#include <hip/hip_runtime.h>

typedef __attribute__((ext_vector_type(8))) short bf16x8;
typedef __attribute__((ext_vector_type(4))) float f32x4;
typedef __attribute__((ext_vector_type(4))) unsigned short u16x4;

#define MFMA16(a, b, c) __builtin_amdgcn_mfma_f32_16x16x32_bf16((a), (b), (c), 0, 0, 0)

__device__ __forceinline__ unsigned short f2bf(float f) {
    union { float f; unsigned int u; } x; x.f = f;
    unsigned int r = x.u + 0x7FFFu + ((x.u >> 16) & 1u);
    return (unsigned short)(r >> 16);
}
__device__ __forceinline__ float bf2f(unsigned short h) {
    union { unsigned int u; float f; } x; x.u = ((unsigned int)h) << 16;
    return x.f;
}
__device__ __forceinline__ void gload_lds16(const void* g, void* l) {
    __builtin_amdgcn_global_load_lds(
        (const __attribute__((address_space(1))) unsigned int*)g,
        (__attribute__((address_space(3))) unsigned int*)l,
        16, 0, 0);
}

// ---- x (fp32) -> bf16 cast, same layout ----
__global__ void cast_x(const float* __restrict__ in, unsigned short* __restrict__ hi,
                       int n) {
    int i = (blockIdx.x * blockDim.x + threadIdx.x) * 4;
    if (i >= n) return;
    float4 v = *(const float4*)(in + i);
    float vv[4] = {v.x, v.y, v.z, v.w};
    u16x4 h;
#pragma unroll
    for (int j = 0; j < 4; ++j) h[j] = f2bf(vv[j]);
    *(u16x4*)(hi + i) = h;
}

// ---- transpose fp32 [K][N] -> bf16 [N][K] ----
__global__ void tcast_k(const float* __restrict__ in, unsigned short* __restrict__ out,
                        int K, int N) {
    __shared__ float tile[64][65];
    int n0 = blockIdx.x * 64, k0 = blockIdx.y * 64;
    for (int i = threadIdx.x; i < 4096; i += 256) {
        int r = i >> 6, c = i & 63;
        tile[r][c] = in[(size_t)(k0 + r) * N + n0 + c];
    }
    __syncthreads();
    for (int i = threadIdx.x; i < 4096; i += 256) {
        int r = i >> 6, c = i & 63;
        out[(size_t)(n0 + r) * K + k0 + c] = f2bf(tile[c][r]);
    }
}

// ---- QKV GEMM, plain bf16 (m97 structure), scatter epilogue ----
__global__ __launch_bounds__(256, 2) void gemm_qkv(
    const unsigned short* __restrict__ A,    // 8192 x 1024
    const unsigned short* __restrict__ Bt,   // 3072 x 1024
    unsigned short* __restrict__ qout, unsigned short* __restrict__ kout,
    unsigned short* __restrict__ vtout) {
    const int K = 1024;
    __shared__ __align__(16) unsigned short sA[4096], sB[4096];
    int tid = threadIdx.x, lane = tid & 63, w = tid >> 6;
    int c = lane & 15, quad = lane >> 4;
    int wm = (w >> 1) * 64, wn = (w & 1) * 64;
    int m0 = blockIdx.y * 128, n0 = blockIdx.x * 128;

    f32x4 acc[4][4];
#pragma unroll
    for (int i = 0; i < 4; i++)
#pragma unroll
        for (int j = 0; j < 4; j++) acc[i][j] = (f32x4){0.f, 0.f, 0.f, 0.f};

    int c0 = tid, c1 = 256 + tid;
    int r0 = c0 >> 2, kc0 = (c0 & 3) * 8;
    int r1 = c1 >> 2, kc1 = (c1 & 3) * 8;

    for (int kk = 0; kk < K; kk += 32) {
        gload_lds16(A + (size_t)(m0 + r0) * K + kk + kc0, &sA[c0 * 8]);
        gload_lds16(A + (size_t)(m0 + r1) * K + kk + kc1, &sA[c1 * 8]);
        gload_lds16(Bt + (size_t)(n0 + r0) * K + kk + kc0, &sB[c0 * 8]);
        gload_lds16(Bt + (size_t)(n0 + r1) * K + kk + kc1, &sB[c1 * 8]);
        __syncthreads();
        bf16x8 af[4], bfr[4];
#pragma unroll
        for (int mt = 0; mt < 4; ++mt)
            af[mt] = *(const bf16x8*)&sA[(wm + mt * 16 + c) * 32 + quad * 8];
#pragma unroll
        for (int nt = 0; nt < 4; ++nt)
            bfr[nt] = *(const bf16x8*)&sB[(wn + nt * 16 + c) * 32 + quad * 8];
#pragma unroll
        for (int mt = 0; mt < 4; ++mt)
#pragma unroll
            for (int nt = 0; nt < 4; ++nt)
                acc[mt][nt] = MFMA16(af[mt], bfr[nt], acc[mt][nt]);
        __syncthreads();
    }

    const float QSCALE = 0.1803368801111601f;  // log2(e) / sqrt(64)
#pragma unroll
    for (int mt = 0; mt < 4; ++mt) {
#pragma unroll
        for (int nt = 0; nt < 4; ++nt) {
#pragma unroll
            for (int r = 0; r < 4; ++r) {
                int row = m0 + wm + mt * 16 + quad * 4 + r;
                int col = n0 + wn + nt * 16 + c;
                float v = acc[mt][nt][r];
                int which = col >> 10;
                int h = (col >> 6) & 15;
                int d = col & 63;
                int b = row >> 11;
                int t = row & 2047;
                size_t bh_ = (size_t)(b * 16 + h);
                if (which == 0)
                    qout[(bh_ * 2048 + t) * 64 + d] = f2bf(v * QSCALE);
                else if (which == 1)
                    kout[(bh_ * 2048 + t) * 64 + d] = f2bf(v);
                else
                    vtout[(bh_ * 64 + d) * 2048 + t] = f2bf(v);
            }
        }
    }
}

// ---- output GEMM, plain bf16, fp32 store ----
__global__ __launch_bounds__(256, 2) void gemm2_bt(
    const unsigned short* __restrict__ A,    // 8192 x 1024 bf16
    const unsigned short* __restrict__ Bt,   // 1024 x 1024 bf16
    float* __restrict__ out) {
    const int K = 1024, N = 1024;
    __shared__ __align__(16) unsigned short sA[4096], sB[4096];
    int tid = threadIdx.x, lane = tid & 63, w = tid >> 6;
    int c = lane & 15, quad = lane >> 4;
    int wm = (w >> 1) * 64, wn = (w & 1) * 64;
    int m0 = blockIdx.y * 128, n0 = blockIdx.x * 128;

    f32x4 acc[4][4];
#pragma unroll
    for (int i = 0; i < 4; i++)
#pragma unroll
        for (int j = 0; j < 4; j++) acc[i][j] = (f32x4){0.f, 0.f, 0.f, 0.f};

    int c0 = tid, c1 = 256 + tid;
    int r0 = c0 >> 2, kc0 = (c0 & 3) * 8;
    int r1 = c1 >> 2, kc1 = (c1 & 3) * 8;

    for (int kk = 0; kk < K; kk += 32) {
        gload_lds16(A + (size_t)(m0 + r0) * K + kk + kc0, &sA[c0 * 8]);
        gload_lds16(A + (size_t)(m0 + r1) * K + kk + kc1, &sA[c1 * 8]);
        gload_lds16(Bt + (size_t)(n0 + r0) * K + kk + kc0, &sB[c0 * 8]);
        gload_lds16(Bt + (size_t)(n0 + r1) * K + kk + kc1, &sB[c1 * 8]);
        __syncthreads();
        bf16x8 af[4], bfr[4];
#pragma unroll
        for (int mt = 0; mt < 4; ++mt)
            af[mt] = *(const bf16x8*)&sA[(wm + mt * 16 + c) * 32 + quad * 8];
#pragma unroll
        for (int nt = 0; nt < 4; ++nt)
            bfr[nt] = *(const bf16x8*)&sB[(wn + nt * 16 + c) * 32 + quad * 8];
#pragma unroll
        for (int mt = 0; mt < 4; ++mt)
#pragma unroll
            for (int nt = 0; nt < 4; ++nt)
                acc[mt][nt] = MFMA16(af[mt], bfr[nt], acc[mt][nt]);
        __syncthreads();
    }

#pragma unroll
    for (int mt = 0; mt < 4; ++mt)
#pragma unroll
        for (int nt = 0; nt < 4; ++nt)
#pragma unroll
            for (int r = 0; r < 4; ++r) {
                int row = m0 + wm + mt * 16 + quad * 4 + r;
                int col = n0 + wn + nt * 16 + c;
                out[(size_t)row * N + col] = acc[mt][nt][r];
            }
}

// ---- causal flash attention, S^T/O^T, 128-row Q tiles, double-buffered K/V ----
// Wave w owns q-rows {q0 + g*64 + w*16 + c} for g=0,1. K-tile = 64 keys.
// One __syncthreads per K-tile; next tile prefetched to regs during compute.
// Block pairs q-tiles (j, 15-j): every block runs exactly 34 K-tile iters.
#define SSTR 72
__global__ __launch_bounds__(256, 2) void attn_k(
    const unsigned short* __restrict__ q,
    const unsigned short* __restrict__ k,
    const unsigned short* __restrict__ vt,
    unsigned short* __restrict__ ctx) {
    const int T = 2048, D = 64;
    __shared__ __align__(16) unsigned short sK[2][64 * SSTR];  // [key][d]
    __shared__ __align__(16) unsigned short sV[2][64 * SSTR];  // [d][key]
    __shared__ __align__(16) unsigned short sP[4][32 * SSTR];  // per-wave [qloc][key]

    int tid = threadIdx.x, lane = tid & 63, w = tid >> 6;
    int c = lane & 15, quad = lane >> 4;
    int pair = blockIdx.x, bh = blockIdx.y;

    const unsigned short* qh = q + (size_t)bh * T * D;
    const unsigned short* kh = k + (size_t)bh * T * D;
    const unsigned short* vh = vt + (size_t)bh * D * T;
    unsigned short* sPw = sP[w];
    int b = bh >> 4, hh = bh & 15;

    // staging coords: K row=lane, d=w*8 (+32); V row=dv (+32), keys tcv..tcv+7
    int dv = tid >> 3, tcv = (tid & 7) * 8;

    for (int half = 0; half < 2; ++half) {
        int jt = half ? (15 - pair) : pair;  // 128-row q-tile index
        int q0 = jt * 128;
        int nkt = 2 * jt + 2;                // # of 64-key tiles
        int qrow[2] = {q0 + w * 16 + c, q0 + 64 + w * 16 + c};

        bf16x8 bq[2][2];
#pragma unroll
        for (int g = 0; g < 2; ++g) {
            bq[g][0] = *(const bf16x8*)&qh[(size_t)qrow[g] * D + quad * 8];
            bq[g][1] = *(const bf16x8*)&qh[(size_t)qrow[g] * D + 32 + quad * 8];
        }

        f32x4 o[2][4];
#pragma unroll
        for (int g = 0; g < 2; ++g)
#pragma unroll
            for (int mt = 0; mt < 4; ++mt) o[g][mt] = (f32x4){0.f, 0.f, 0.f, 0.f};
        float m_i[2] = {-1.0e30f, -1.0e30f}, l_i[2] = {0.f, 0.f};

        // preload tile 0 into regs
        bf16x8 kr0 = *(const bf16x8*)&kh[(size_t)lane * D + w * 8];
        bf16x8 kr1 = *(const bf16x8*)&kh[(size_t)lane * D + w * 8 + 32];
        bf16x8 vr0 = *(const bf16x8*)&vh[(size_t)dv * T + tcv];
        bf16x8 vr1 = *(const bf16x8*)&vh[(size_t)(dv + 32) * T + tcv];
        __syncthreads();  // prior half's reads of buf0 complete
        *(bf16x8*)&sK[0][lane * SSTR + w * 8] = kr0;
        *(bf16x8*)&sK[0][lane * SSTR + w * 8 + 32] = kr1;
        *(bf16x8*)&sV[0][dv * SSTR + tcv] = vr0;
        *(bf16x8*)&sV[0][(dv + 32) * SSTR + tcv] = vr1;
        __syncthreads();

        for (int kt = 0; kt < nkt; ++kt) {
            int cur = kt & 1;
            int kb = kt * 64;
            if (kt + 1 < nkt) {  // issue prefetch of next tile
                int kb2 = (kt + 1) * 64;
                kr0 = *(const bf16x8*)&kh[(size_t)(kb2 + lane) * D + w * 8];
                kr1 = *(const bf16x8*)&kh[(size_t)(kb2 + lane) * D + w * 8 + 32];
                vr0 = *(const bf16x8*)&vh[(size_t)dv * T + kb2 + tcv];
                vr1 = *(const bf16x8*)&vh[(size_t)(dv + 32) * T + kb2 + tcv];
            }
            const unsigned short* sKc = sK[cur];
            const unsigned short* sVc = sV[cur];

            // K fragments read once, reused by both q-groups
            bf16x8 ak0[4], ak1[4];
#pragma unroll
            for (int mt = 0; mt < 4; ++mt) {
                ak0[mt] = *(const bf16x8*)&sKc[(mt * 16 + c) * SSTR + quad * 8];
                ak1[mt] = *(const bf16x8*)&sKc[(mt * 16 + c) * SSTR + 32 + quad * 8];
            }

#pragma unroll
            for (int g = 0; g < 2; ++g) {
                f32x4 st[4];
#pragma unroll
                for (int mt = 0; mt < 4; ++mt) {
                    f32x4 z = (f32x4){0.f, 0.f, 0.f, 0.f};
                    z = MFMA16(ak0[mt], bq[g][0], z);
                    z = MFMA16(ak1[mt], bq[g][1], z);
                    st[mt] = z;
                }
                int qr = qrow[g];
                if (kb + 63 > qr) {  // causal mask (key_abs > qrow_abs)
#pragma unroll
                    for (int mt = 0; mt < 4; ++mt)
#pragma unroll
                        for (int r = 0; r < 4; ++r)
                            if (kb + mt * 16 + quad * 4 + r > qr) st[mt][r] = -1.0e30f;
                }
                // per-lane softmax over 16 keys, combine across quads (rows 16/32)
                float vmax = fmaxf(
                    fmaxf(fmaxf(fmaxf(st[0][0], st[0][1]), fmaxf(st[0][2], st[0][3])),
                          fmaxf(fmaxf(st[1][0], st[1][1]), fmaxf(st[1][2], st[1][3]))),
                    fmaxf(fmaxf(fmaxf(st[2][0], st[2][1]), fmaxf(st[2][2], st[2][3])),
                          fmaxf(fmaxf(st[3][0], st[3][1]), fmaxf(st[3][2], st[3][3]))));
                vmax = fmaxf(vmax, __shfl_xor(vmax, 16));
                vmax = fmaxf(vmax, __shfl_xor(vmax, 32));
                float mnew = fmaxf(m_i[g], vmax);
                float alpha = __builtin_exp2f(m_i[g] - mnew);
                float rs = 0.f;
#pragma unroll
                for (int mt = 0; mt < 4; ++mt) {
                    u16x4 pb;
#pragma unroll
                    for (int r = 0; r < 4; ++r) {
                        float p = __builtin_exp2f(st[mt][r] - mnew);
                        unsigned short pw = f2bf(p);
                        rs += bf2f(pw);
                        pb[r] = pw;
                    }
                    *(u16x4*)&sPw[(g * 16 + c) * SSTR + mt * 16 + quad * 4] = pb;
                }
                rs += __shfl_xor(rs, 16);
                rs += __shfl_xor(rs, 32);
                l_i[g] = l_i[g] * alpha + rs;
                m_i[g] = mnew;
#pragma unroll
                for (int mt = 0; mt < 4; ++mt)
#pragma unroll
                    for (int r = 0; r < 4; ++r) o[g][mt][r] *= alpha;
            }

            // O^T += V^T · P^T   (av shared across groups)
#pragma unroll
            for (int ch = 0; ch < 2; ++ch) {
                bf16x8 av[4];
#pragma unroll
                for (int mt = 0; mt < 4; ++mt)
                    av[mt] = *(const bf16x8*)&sVc[(mt * 16 + c) * SSTR + ch * 32 + quad * 8];
#pragma unroll
                for (int g = 0; g < 2; ++g) {
                    bf16x8 bp = *(const bf16x8*)&sPw[(g * 16 + c) * SSTR + ch * 32 + quad * 8];
#pragma unroll
                    for (int mt = 0; mt < 4; ++mt)
                        o[g][mt] = MFMA16(av[mt], bp, o[g][mt]);
                }
            }

            if (kt + 1 < nkt) {  // commit prefetched tile, single barrier
                unsigned short* sKn = sK[1 - cur];
                unsigned short* sVn = sV[1 - cur];
                *(bf16x8*)&sKn[lane * SSTR + w * 8] = kr0;
                *(bf16x8*)&sKn[lane * SSTR + w * 8 + 32] = kr1;
                *(bf16x8*)&sVn[dv * SSTR + tcv] = vr0;
                *(bf16x8*)&sVn[(dv + 32) * SSTR + tcv] = vr1;
                __syncthreads();
            }
        }

        // epilogue: lane owns qrow[g]; d = mt*16 + quad*4 + r
#pragma unroll
        for (int g = 0; g < 2; ++g) {
            float inv = 1.0f / l_i[g];
#pragma unroll
            for (int mt = 0; mt < 4; ++mt) {
                u16x4 ob;
#pragma unroll
                for (int r = 0; r < 4; ++r) ob[r] = f2bf(o[g][mt][r] * inv);
                *(u16x4*)&ctx[(size_t)(b * T + qrow[g]) * 1024 + hh * 64 + mt * 16 + quad * 4] = ob;
            }
        }
    }
}

extern "C" void kernel_launch(void* const* d_in, const int* in_sizes, int n_in,
                              void* d_out, int out_size, void* d_ws, size_t ws_size,
                              hipStream_t stream) {
    const float* x     = (const float*)d_in[0];  // (4,2048,1024) fp32
    const float* w_qkv = (const float*)d_in[1];  // (1024,3072) fp32
    const float* w_out = (const float*)d_in[2];  // (1024,1024) fp32
    float* out = (float*)d_out;                  // (4,2048,1024) fp32

    char* ws = (char*)d_ws;
    unsigned short* wqkvt = (unsigned short*)(ws + 0);          //  6.29 MB
    unsigned short* woutt = (unsigned short*)(ws + 6291456);    //  2.10 MB
    unsigned short* x_bf  = (unsigned short*)(ws + 8388608);    // 16.78 MB
    unsigned short* qb    = (unsigned short*)(ws + 25165824);   // 16.78 MB
    unsigned short* kb    = (unsigned short*)(ws + 41943040);   // 16.78 MB
    unsigned short* vtb   = (unsigned short*)(ws + 58720256);   // 16.78 MB
    unsigned short* ctx   = (unsigned short*)(ws + 8388608);    // reuse x_bf slot

    cast_x<<<8192, 256, 0, stream>>>(x, x_bf, 8388608);
    tcast_k<<<dim3(48, 16), 256, 0, stream>>>(w_qkv, wqkvt, 1024, 3072);
    tcast_k<<<dim3(16, 16), 256, 0, stream>>>(w_out, woutt, 1024, 1024);
    gemm_qkv<<<dim3(24, 64), 256, 0, stream>>>(x_bf, wqkvt, qb, kb, vtb);
    attn_k<<<dim3(8, 64), 256, 0, stream>>>(qb, kb, vtb, ctx);
    gemm2_bt<<<dim3(8, 64), 256, 0, stream>>>(ctx, woutt, out);
}